// Round 16
// baseline (406.310 us; speedup 1.0000x reference)
//
#include <hip/hip_runtime.h>

#define HID    128
#define SEQ    512
#define BATCH  256
#define DIM    300
#define VOCAB  50000

typedef short bf16x8 __attribute__((ext_vector_type(8)));   // 8 bf16 = 4 VGPR
typedef float f32x4  __attribute__((ext_vector_type(4)));

#define KP     320      // padded K (10 x 32)
#define LST    328      // LDS row stride in bf16 (656 B, 16B-aligned)
#define TROWS  32       // vocab rows per tile
#define NTILES ((VOCAB + TROWS - 1) / TROWS)   // 1563

__device__ __forceinline__ unsigned bf16_rtne(float v)
{
    unsigned u = __float_as_uint(v);
    return (u + 0x7FFFu + ((u >> 16) & 1u)) >> 16;
}

// ---------------------------------------------------------------------------
// Kernel A (R15-proven, ~33 µs): persistent MFMA proj, W staged once,
// emb double-buffered. Byte-identical to R15.
// ---------------------------------------------------------------------------
__global__ __launch_bounds__(512)
void proj_persist(const float* __restrict__ emb,
                  const float* __restrict__ Wih,
                  const float* __restrict__ bih,
                  const float* __restrict__ bhh,
                  float* __restrict__ P)
{
    __shared__ unsigned short Bt[128 * LST];       // W_ih bf16 (84 KB)
    __shared__ unsigned short At[2 * TROWS * LST]; // emb dbuf (2 x 21 KB)

    const int t   = threadIdx.x;
    const int bid = blockIdx.x;

    for (int c = t; c < 128 * 40; c += 512) {
        const int row = c / 40;
        const int ch  = c - row * 40;
        const float* src = Wih + (size_t)row * DIM;
        const int k0 = ch * 8;
        unsigned p0, p1, p2, p3;
        if (k0 + 8 <= DIM) {
            const float4 a = *(const float4*)(src + k0);
            const float4 b = *(const float4*)(src + k0 + 4);
            p0 = bf16_rtne(a.x) | (bf16_rtne(a.y) << 16);
            p1 = bf16_rtne(a.z) | (bf16_rtne(a.w) << 16);
            p2 = bf16_rtne(b.x) | (bf16_rtne(b.y) << 16);
            p3 = bf16_rtne(b.z) | (bf16_rtne(b.w) << 16);
        } else {
            unsigned q[8];
            #pragma unroll
            for (int e = 0; e < 8; ++e) {
                const int k = k0 + e;
                q[e] = (k < DIM) ? bf16_rtne(src[k]) : 0u;
            }
            p0 = q[0] | (q[1] << 16);  p1 = q[2] | (q[3] << 16);
            p2 = q[4] | (q[5] << 16);  p3 = q[6] | (q[7] << 16);
        }
        uint4 o = {p0, p1, p2, p3};
        *(uint4*)(&Bt[row * LST + k0]) = o;
    }

#define STAGE_EMB(tl, bf) do {                                                \
        const int v0_ = (tl) * TROWS;                                         \
        for (int c = t; c < TROWS * 40; c += 512) {                           \
            const int row = c / 40;                                           \
            const int ch  = c - row * 40;                                     \
            int grow = v0_ + row; if (grow > VOCAB - 1) grow = VOCAB - 1;     \
            const float* src = emb + (size_t)grow * DIM;                      \
            const int k0 = ch * 8;                                            \
            unsigned p0, p1, p2, p3;                                          \
            if (k0 + 8 <= DIM) {                                              \
                const float4 a = *(const float4*)(src + k0);                  \
                const float4 b = *(const float4*)(src + k0 + 4);              \
                p0 = bf16_rtne(a.x) | (bf16_rtne(a.y) << 16);                 \
                p1 = bf16_rtne(a.z) | (bf16_rtne(a.w) << 16);                 \
                p2 = bf16_rtne(b.x) | (bf16_rtne(b.y) << 16);                 \
                p3 = bf16_rtne(b.z) | (bf16_rtne(b.w) << 16);                 \
            } else {                                                          \
                unsigned q[8];                                                \
                _Pragma("unroll")                                             \
                for (int e = 0; e < 8; ++e) {                                 \
                    const int k = k0 + e;                                     \
                    q[e] = (k < DIM) ? bf16_rtne(src[k]) : 0u;                \
                }                                                             \
                p0 = q[0] | (q[1] << 16);  p1 = q[2] | (q[3] << 16);          \
                p2 = q[4] | (q[5] << 16);  p3 = q[6] | (q[7] << 16);          \
            }                                                                 \
            uint4 o = {p0, p1, p2, p3};                                       \
            *(uint4*)(&At[(bf) * (TROWS * LST) + row * LST + k0]) = o;        \
        }                                                                     \
    } while (0)

    const int lane = t & 63;
    const int w    = t >> 6;
    const int mt   = w >> 2;
    const int np   = w & 3;
    const int lm   = lane & 15;
    const int kg   = lane >> 4;

    STAGE_EMB(bid, 0);
    __syncthreads();

    int buf = 0;
    for (int tile = bid; tile < NTILES; tile += 256) {
        if (tile + 256 < NTILES) STAGE_EMB(tile + 256, buf ^ 1);

        const unsigned short* arow = &At[buf * (TROWS * LST)
                                         + (mt * 16 + lm) * LST + kg * 8];
        const unsigned short* brow = &Bt[(np * 32 + lm) * LST + kg * 8];

        f32x4 acc0 = {0.f,0.f,0.f,0.f}, acc1 = {0.f,0.f,0.f,0.f};
        #pragma unroll
        for (int k0 = 0; k0 < KP; k0 += 32) {
            const bf16x8 af = *(const bf16x8*)(arow + k0);
            const bf16x8 b0 = *(const bf16x8*)(brow + k0);
            const bf16x8 b1 = *(const bf16x8*)(brow + 16 * LST + k0);
            acc0 = __builtin_amdgcn_mfma_f32_16x16x32_bf16(af, b0, acc0, 0, 0, 0);
            acc1 = __builtin_amdgcn_mfma_f32_16x16x32_bf16(af, b1, acc1, 0, 0, 0);
        }

        const int rbase = tile * TROWS + mt * 16 + kg * 4;
        #pragma unroll
        for (int nt2 = 0; nt2 < 2; ++nt2) {
            const int h = (np * 2 + nt2) * 16 + lm;
            const float bb = bih[h] + bhh[h];
            const f32x4 a = nt2 ? acc1 : acc0;
            #pragma unroll
            for (int r = 0; r < 4; ++r) {
                const int row = rbase + r;
                if (row < VOCAB) P[(size_t)row * HID + h] = a[r] + bb;
            }
        }

        __syncthreads();
        buf ^= 1;
    }
#undef STAGE_EMB
}

// ---------------------------------------------------------------------------
// Kernel B: TWO-ELEMENT INTERLEAVED RNN. grid=128, 512 thr, R8 thread map
// (i=t>>2, kq=t&3) and R8 STEP body byte-for-byte. Steps alternate batch
// elements A,B; ONE barrier per A+B pair (RAW/WAR analysis: hA written in
// pair n is read in pair n+1 with the pair barrier between; ditto hB).
// B's step fills A's write->read latency gap (the measured S ~550 cyc that
// lockstepped waves cannot hide). xb staging: 32-step chunks per element,
// double-buffered (same inst rate as R8's 64-step chunks).
// ---------------------------------------------------------------------------
__device__ __forceinline__ float quad_sum(float v)
{
    int x1 = __builtin_amdgcn_update_dpp(0, __float_as_int(v), 0xB1, 0xF, 0xF, true);
    v += __int_as_float(x1);
    int x2 = __builtin_amdgcn_update_dpp(0, __float_as_int(v), 0x4E, 0xF, 0xF, true);
    v += __int_as_float(x2);
    return v;
}

__global__ __launch_bounds__(512)
void rnn2_kernel(const int* __restrict__ x,
                 const float* __restrict__ Whh,
                 const float* __restrict__ P,
                 const float* __restrict__ fcw,
                 const float* __restrict__ fcb,
                 float* __restrict__ out)
{
    __shared__ float hA0[HID], hA1[HID];
    __shared__ float hB0[HID], hB1[HID];
    __shared__ int   toffA[SEQ], toffB[SEQ];
    __shared__ float xbA[2 * 32 * HID];   // 32 KB
    __shared__ float xbB[2 * 32 * HID];   // 32 KB
    __shared__ float red[HID];

    const int t  = threadIdx.x;
    const int b2 = blockIdx.x * 2;        // elements b2, b2+1
    const int i  = t >> 2;
    const int kq = t & 3;

    toffA[t] = x[(size_t)b2 * SEQ + t] * HID;
    toffB[t] = x[(size_t)(b2 + 1) * SEQ + t] * HID;
    if (t < HID) { hA0[t] = 0.f; hB0[t] = 0.f; }

    float4 w[8];
    #pragma unroll
    for (int j = 0; j < 8; ++j) {
        const int pj = (j + 2 * kq) & 7;
        w[j] = *(const float4*)(Whh + (size_t)i * HID + kq * 32 + pj * 4);
    }
    __syncthreads();

// stage 32-step chunk cn of element E into xb half bf (2 float4/thread)
#define STAGE2(TOFF, XB, cn, bf) do {                                         \
        _Pragma("unroll")                                                     \
        for (int q_ = 0; q_ < 2; ++q_) {                                      \
            const int idx_ = t + q_ * 512;                                    \
            const int row_ = idx_ >> 5;                                       \
            const int c4_  = idx_ & 31;                                       \
            const int off_ = (TOFF)[(cn) * 32 + row_] + c4_ * 4;              \
            const float4 v_ = *(const float4*)(P + off_);                     \
            *(float4*)(&(XB)[(bf) * (32 * HID) + row_ * HID + c4_ * 4]) = v_; \
        }                                                                     \
    } while (0)

    STAGE2(toffA, xbA, 0, 0);
    STAGE2(toffB, xbB, 0, 0);
    __syncthreads();

    float hmaxA = -3.0e38f, hsumA = 0.f;
    float hmaxB = -3.0e38f, hsumB = 0.f;

// R8 STEP body, parameterized pooling state, NO trailing barrier
#define STEP2(HRD, HWR, XPTR, SOFF, HMAX, HSUM) do {                          \
        const float xt = (XPTR)[(SOFF) * HID];                                \
        float ac0=0.f,ac1=0.f,ac2=0.f,ac3=0.f,ac4=0.f,ac5=0.f,ac6=0.f,ac7=0.f;\
        _Pragma("unroll")                                                     \
        for (int j = 0; j < 8; ++j) {                                         \
            const int pj = (j + 2 * kq) & 7;                                  \
            const float4 h4 = *(const float4*)((HRD) + kq * 32 + pj * 4);     \
            float* ap = (j==0)?&ac0:(j==1)?&ac1:(j==2)?&ac2:(j==3)?&ac3       \
                       :(j==4)?&ac4:(j==5)?&ac5:(j==6)?&ac6:&ac7;             \
            *ap = fmaf(w[j].x, h4.x, *ap);                                    \
            *ap = fmaf(w[j].y, h4.y, *ap);                                    \
            *ap = fmaf(w[j].z, h4.z, *ap);                                    \
            *ap = fmaf(w[j].w, h4.w, *ap);                                    \
        }                                                                     \
        float acc = ((ac0+ac1)+(ac2+ac3)) + ((ac4+ac5)+(ac6+ac7));            \
        acc = quad_sum(acc);                                                  \
        const float z = xt + acc;                                             \
        const float e = __builtin_amdgcn_exp2f(z * 2.8853900817779268f);      \
        const float hnew = fmaf(-2.f, __builtin_amdgcn_rcpf(e + 1.f), 1.f);   \
        HMAX = fmaxf(HMAX, hnew);                                             \
        HSUM += hnew;                                                         \
        (HWR)[i] = hnew;                                                      \
    } while (0)

    for (int c = 0; c < 16; ++c) {
        if (c < 15) {
            STAGE2(toffA, xbA, c + 1, (c + 1) & 1);
            STAGE2(toffB, xbB, c + 1, (c + 1) & 1);
        }
        const float* xpA = &xbA[(c & 1) * (32 * HID) + i];
        const float* xpB = &xbB[(c & 1) * (32 * HID) + i];
        #pragma unroll 2
        for (int u = 0; u < 16; ++u) {
            STEP2(hA0, hA1, xpA, u * 2,     hmaxA, hsumA);
            STEP2(hB0, hB1, xpB, u * 2,     hmaxB, hsumB);
            __syncthreads();                     // one barrier per A+B pair
            STEP2(hA1, hA0, xpA, u * 2 + 1, hmaxA, hsumA);
            STEP2(hB1, hB0, xpB, u * 2 + 1, hmaxB, hsumB);
            __syncthreads();
        }
    }
#undef STEP2
#undef STAGE2

    // pooling + FC for element A
    if (kq == 0)
        red[i] = fcw[i] * hmaxA + fcw[HID + i] * (hsumA * (1.f / 512.f));
    __syncthreads();
    if (t < 64) {
        float v = red[t] + red[t + 64];
        #pragma unroll
        for (int m = 32; m >= 1; m >>= 1) v += __shfl_xor(v, m);
        if (t == 0) out[b2] = v + fcb[0];
    }
    __syncthreads();
    // pooling + FC for element B
    if (kq == 0)
        red[i] = fcw[i] * hmaxB + fcw[HID + i] * (hsumB * (1.f / 512.f));
    __syncthreads();
    if (t < 64) {
        float v = red[t] + red[t + 64];
        #pragma unroll
        for (int m = 32; m >= 1; m >>= 1) v += __shfl_xor(v, m);
        if (t == 0) out[b2 + 1] = v + fcb[0];
    }
}

// ---------------------------------------------------------------------------
extern "C" void kernel_launch(void* const* d_in, const int* in_sizes, int n_in,
                              void* d_out, int out_size, void* d_ws, size_t ws_size,
                              hipStream_t stream)
{
    const int*   x   = (const int*)  d_in[0];
    const float* emb = (const float*)d_in[1];
    const float* Wih = (const float*)d_in[2];
    const float* Whh = (const float*)d_in[3];
    const float* bih = (const float*)d_in[4];
    const float* bhh = (const float*)d_in[5];
    const float* fcw = (const float*)d_in[6];
    const float* fcb = (const float*)d_in[7];

    float* P = (float*)d_ws;   // exactly VOCAB*HID*4 = 25.6 MB (R1-proven)

    proj_persist<<<256, 512, 0, stream>>>(emb, Wih, bih, bhh, P);
    rnn2_kernel<<<BATCH / 2, 512, 0, stream>>>(x, Whh, P, fcw, fcb, (float*)d_out);
}

// Round 18
// 183.015 us; speedup vs baseline: 2.2201x; 2.2201x over previous
//
#include <hip/hip_runtime.h>

#define HID    128
#define SEQ    512
#define BATCH  256
#define DIM    300
#define VOCAB  50000

typedef short bf16x8 __attribute__((ext_vector_type(8)));   // 8 bf16 = 4 VGPR
typedef float f32x4  __attribute__((ext_vector_type(4)));
typedef __fp16 half2_t __attribute__((ext_vector_type(2))); // matches cvt_pkrtz

#define KP     320      // padded K (10 x 32)
#define LST    328      // LDS row stride in bf16 (656 B, 16B-aligned)
#define TROWS  32       // vocab rows per tile
#define NTILES ((VOCAB + TROWS - 1) / TROWS)   // 1563

__device__ __forceinline__ unsigned bf16_rtne(float v)
{
    unsigned u = __float_as_uint(v);
    return (u + 0x7FFFu + ((u >> 16) & 1u)) >> 16;
}

// ---------------------------------------------------------------------------
// Kernel A (R15-proven, ~33 µs): persistent MFMA proj — byte-identical.
// ---------------------------------------------------------------------------
__global__ __launch_bounds__(512)
void proj_persist(const float* __restrict__ emb,
                  const float* __restrict__ Wih,
                  const float* __restrict__ bih,
                  const float* __restrict__ bhh,
                  float* __restrict__ P)
{
    __shared__ unsigned short Bt[128 * LST];       // W_ih bf16 (84 KB)
    __shared__ unsigned short At[2 * TROWS * LST]; // emb dbuf (2 x 21 KB)

    const int t   = threadIdx.x;
    const int bid = blockIdx.x;

    for (int c = t; c < 128 * 40; c += 512) {
        const int row = c / 40;
        const int ch  = c - row * 40;
        const float* src = Wih + (size_t)row * DIM;
        const int k0 = ch * 8;
        unsigned p0, p1, p2, p3;
        if (k0 + 8 <= DIM) {
            const float4 a = *(const float4*)(src + k0);
            const float4 b = *(const float4*)(src + k0 + 4);
            p0 = bf16_rtne(a.x) | (bf16_rtne(a.y) << 16);
            p1 = bf16_rtne(a.z) | (bf16_rtne(a.w) << 16);
            p2 = bf16_rtne(b.x) | (bf16_rtne(b.y) << 16);
            p3 = bf16_rtne(b.z) | (bf16_rtne(b.w) << 16);
        } else {
            unsigned q[8];
            #pragma unroll
            for (int e = 0; e < 8; ++e) {
                const int k = k0 + e;
                q[e] = (k < DIM) ? bf16_rtne(src[k]) : 0u;
            }
            p0 = q[0] | (q[1] << 16);  p1 = q[2] | (q[3] << 16);
            p2 = q[4] | (q[5] << 16);  p3 = q[6] | (q[7] << 16);
        }
        uint4 o = {p0, p1, p2, p3};
        *(uint4*)(&Bt[row * LST + k0]) = o;
    }

#define STAGE_EMB(tl, bf) do {                                                \
        const int v0_ = (tl) * TROWS;                                         \
        for (int c = t; c < TROWS * 40; c += 512) {                           \
            const int row = c / 40;                                           \
            const int ch  = c - row * 40;                                     \
            int grow = v0_ + row; if (grow > VOCAB - 1) grow = VOCAB - 1;     \
            const float* src = emb + (size_t)grow * DIM;                      \
            const int k0 = ch * 8;                                            \
            unsigned p0, p1, p2, p3;                                          \
            if (k0 + 8 <= DIM) {                                              \
                const float4 a = *(const float4*)(src + k0);                  \
                const float4 b = *(const float4*)(src + k0 + 4);              \
                p0 = bf16_rtne(a.x) | (bf16_rtne(a.y) << 16);                 \
                p1 = bf16_rtne(a.z) | (bf16_rtne(a.w) << 16);                 \
                p2 = bf16_rtne(b.x) | (bf16_rtne(b.y) << 16);                 \
                p3 = bf16_rtne(b.z) | (bf16_rtne(b.w) << 16);                 \
            } else {                                                          \
                unsigned q[8];                                                \
                _Pragma("unroll")                                             \
                for (int e = 0; e < 8; ++e) {                                 \
                    const int k = k0 + e;                                     \
                    q[e] = (k < DIM) ? bf16_rtne(src[k]) : 0u;                \
                }                                                             \
                p0 = q[0] | (q[1] << 16);  p1 = q[2] | (q[3] << 16);          \
                p2 = q[4] | (q[5] << 16);  p3 = q[6] | (q[7] << 16);          \
            }                                                                 \
            uint4 o = {p0, p1, p2, p3};                                       \
            *(uint4*)(&At[(bf) * (TROWS * LST) + row * LST + k0]) = o;        \
        }                                                                     \
    } while (0)

    const int lane = t & 63;
    const int w    = t >> 6;
    const int mt   = w >> 2;
    const int np   = w & 3;
    const int lm   = lane & 15;
    const int kg   = lane >> 4;

    STAGE_EMB(bid, 0);
    __syncthreads();

    int buf = 0;
    for (int tile = bid; tile < NTILES; tile += 256) {
        if (tile + 256 < NTILES) STAGE_EMB(tile + 256, buf ^ 1);

        const unsigned short* arow = &At[buf * (TROWS * LST)
                                         + (mt * 16 + lm) * LST + kg * 8];
        const unsigned short* brow = &Bt[(np * 32 + lm) * LST + kg * 8];

        f32x4 acc0 = {0.f,0.f,0.f,0.f}, acc1 = {0.f,0.f,0.f,0.f};
        #pragma unroll
        for (int k0 = 0; k0 < KP; k0 += 32) {
            const bf16x8 af = *(const bf16x8*)(arow + k0);
            const bf16x8 b0 = *(const bf16x8*)(brow + k0);
            const bf16x8 b1 = *(const bf16x8*)(brow + 16 * LST + k0);
            acc0 = __builtin_amdgcn_mfma_f32_16x16x32_bf16(af, b0, acc0, 0, 0, 0);
            acc1 = __builtin_amdgcn_mfma_f32_16x16x32_bf16(af, b1, acc1, 0, 0, 0);
        }

        const int rbase = tile * TROWS + mt * 16 + kg * 4;
        #pragma unroll
        for (int nt2 = 0; nt2 < 2; ++nt2) {
            const int h = (np * 2 + nt2) * 16 + lm;
            const float bb = bih[h] + bhh[h];
            const f32x4 a = nt2 ? acc1 : acc0;
            #pragma unroll
            for (int r = 0; r < 4; ++r) {
                const int row = rbase + r;
                if (row < VOCAB) P[(size_t)row * HID + h] = a[r] + bb;
            }
        }

        __syncthreads();
        buf ^= 1;
    }
#undef STAGE_EMB
}

// ---------------------------------------------------------------------------
// Kernel B: RNN, R8 chassis, h as F16 pairs in LDS + v_dot2_f32_f16.
// LDS bytes/step halve (R8 measured at the f32 LDS-BW floor); no unpack
// chain (R13's failure mode). W pre-converted via cvt_pkrtz.
// ---------------------------------------------------------------------------
__device__ __forceinline__ float quad_sum(float v)
{
    int x1 = __builtin_amdgcn_update_dpp(0, __float_as_int(v), 0xB1, 0xF, 0xF, true);
    v += __int_as_float(x1);
    int x2 = __builtin_amdgcn_update_dpp(0, __float_as_int(v), 0x4E, 0xF, 0xF, true);
    v += __int_as_float(x2);
    return v;
}

#if defined(__has_builtin)
#  if __has_builtin(__builtin_amdgcn_fdot2)
#    define HAVE_FDOT2 1
#  endif
#endif

__device__ __forceinline__ half2_t u2h(unsigned u)
{
    union { unsigned u; half2_t h; } c; c.u = u; return c.h;
}

__global__ __launch_bounds__(512)
void rnn_kernel(const int* __restrict__ x,
                const float* __restrict__ Whh,
                const float* __restrict__ P,
                const float* __restrict__ fcw,
                const float* __restrict__ fcb,
                float* __restrict__ out)
{
    __shared__ __align__(16) unsigned short h0b[HID];   // f16 h (256 B)
    __shared__ __align__(16) unsigned short h1b[HID];
    __shared__ int   toff[SEQ];
    __shared__ float xb[2 * 64 * HID];
    __shared__ float red[HID];

    const int t  = threadIdx.x;
    const int b  = blockIdx.x;
    const int i  = t >> 2;
    const int kq = t & 3;

    toff[t] = x[b * SEQ + t] * HID;
    if (t < HID) h0b[t] = 0;   // f16 zero

    // W_hh[i][kq*32 + pj*8 .. +8] as 16 packed f16 pairs (pj=(j+kq)&3)
    half2_t wh[16];
    #pragma unroll
    for (int j = 0; j < 4; ++j) {
        const int pj = (j + kq) & 3;
        const float4 vA = *(const float4*)(Whh + (size_t)i * HID + kq * 32 + pj * 8);
        const float4 vB = *(const float4*)(Whh + (size_t)i * HID + kq * 32 + pj * 8 + 4);
        wh[j*4+0] = __builtin_amdgcn_cvt_pkrtz(vA.x, vA.y);
        wh[j*4+1] = __builtin_amdgcn_cvt_pkrtz(vA.z, vA.w);
        wh[j*4+2] = __builtin_amdgcn_cvt_pkrtz(vB.x, vB.y);
        wh[j*4+3] = __builtin_amdgcn_cvt_pkrtz(vB.z, vB.w);
    }
    __syncthreads();

#define STAGE(cn) do {                                                        \
        const int w_ = t >> 6, l_ = t & 63;                                   \
        const int base_ = ((cn) & 1) * (64 * HID);                            \
        _Pragma("unroll")                                                     \
        for (int q_ = 0; q_ < 4; ++q_) {                                      \
            const int row_ = w_ * 8 + q_ * 2 + (l_ >> 5);                     \
            const int col_ = (l_ & 31) * 4;                                   \
            const int off_ = toff[(cn) * 64 + row_] + col_;                   \
            const float4 v_ = *(const float4*)(P + off_);                     \
            *(float4*)(&xb[base_ + row_ * HID + col_]) = v_;                  \
        }                                                                     \
    } while (0)

    STAGE(0);
    __syncthreads();

    float hmax = -3.0e38f, hsum = 0.f;

#if HAVE_FDOT2
#define JBLK(HRD, J, AC) do {                                                 \
        const int pj_ = ((J) + kq) & 3;                                       \
        const uint4 q_ = *(const uint4*)((HRD) + kq * 32 + pj_ * 8);          \
        AC = __builtin_amdgcn_fdot2(wh[(J)*4+0], u2h(q_.x), AC, false);       \
        AC = __builtin_amdgcn_fdot2(wh[(J)*4+1], u2h(q_.y), AC, false);       \
        AC = __builtin_amdgcn_fdot2(wh[(J)*4+2], u2h(q_.z), AC, false);       \
        AC = __builtin_amdgcn_fdot2(wh[(J)*4+3], u2h(q_.w), AC, false);       \
    } while (0)
#else
#define JBLK(HRD, J, AC) do {                                                 \
        const int pj_ = ((J) + kq) & 3;                                       \
        const uint4 q_ = *(const uint4*)((HRD) + kq * 32 + pj_ * 8);          \
        _Pragma("unroll")                                                     \
        for (int e_ = 0; e_ < 4; ++e_) {                                      \
            const unsigned u_ = (e_==0)?q_.x:(e_==1)?q_.y:(e_==2)?q_.z:q_.w;  \
            const half2_t h2_ = u2h(u_);                                      \
            AC = fmaf((float)wh[(J)*4+e_].x, (float)h2_.x, AC);               \
            AC = fmaf((float)wh[(J)*4+e_].y, (float)h2_.y, AC);               \
        }                                                                     \
    } while (0)
#endif

#define STEP(HRD, HWR, XPTR, SOFF) do {                                       \
        const float xt = (XPTR)[(SOFF) * HID];                                \
        float ac0 = 0.f, ac1 = 0.f, ac2 = 0.f, ac3 = 0.f;                     \
        JBLK(HRD, 0, ac0);                                                    \
        JBLK(HRD, 1, ac1);                                                    \
        JBLK(HRD, 2, ac2);                                                    \
        JBLK(HRD, 3, ac3);                                                    \
        float acc = (ac0 + ac1) + (ac2 + ac3);                                \
        acc = quad_sum(acc);                                                  \
        const float z = xt + acc;                                             \
        const float e = __builtin_amdgcn_exp2f(z * 2.8853900817779268f);      \
        const float hnew = fmaf(-2.f, __builtin_amdgcn_rcpf(e + 1.f), 1.f);   \
        hmax = fmaxf(hmax, hnew);                                             \
        hsum += hnew;                                                         \
        union { __fp16 f; unsigned short u; } cv_;                            \
        cv_.f = (__fp16)hnew;                                                 \
        (HWR)[i] = cv_.u;   /* 4 dup lanes: same value, same address */       \
        __syncthreads();                                                      \
    } while (0)

    for (int c = 0; c < 8; ++c) {
        if (c < 7) STAGE(c + 1);
        const float* xp = &xb[(c & 1) * (64 * HID) + i];
        #pragma unroll 4
        for (int u = 0; u < 32; ++u) {
            STEP(h0b, h1b, xp, u * 2);
            STEP(h1b, h0b, xp, u * 2 + 1);
        }
    }
#undef STEP
#undef JBLK
#undef STAGE

    if (kq == 0)
        red[i] = fcw[i] * hmax + fcw[HID + i] * (hsum * (1.f / 512.f));
    __syncthreads();
    if (t < 64) {
        float v = red[t] + red[t + 64];
        #pragma unroll
        for (int m = 32; m >= 1; m >>= 1) v += __shfl_xor(v, m);
        if (t == 0) out[b] = v + fcb[0];
    }
}

// ---------------------------------------------------------------------------
extern "C" void kernel_launch(void* const* d_in, const int* in_sizes, int n_in,
                              void* d_out, int out_size, void* d_ws, size_t ws_size,
                              hipStream_t stream)
{
    const int*   x   = (const int*)  d_in[0];
    const float* emb = (const float*)d_in[1];
    const float* Wih = (const float*)d_in[2];
    const float* Whh = (const float*)d_in[3];
    const float* bih = (const float*)d_in[4];
    const float* bhh = (const float*)d_in[5];
    const float* fcw = (const float*)d_in[6];
    const float* fcb = (const float*)d_in[7];

    float* P = (float*)d_ws;   // exactly VOCAB*HID*4 = 25.6 MB (R1-proven)

    proj_persist<<<256, 512, 0, stream>>>(emb, Wih, bih, bhh, P);
    rnn_kernel<<<BATCH, 512, 0, stream>>>(x, Whh, P, fcw, fcb, (float*)d_out);
}